// Round 3
// baseline (599.277 us; speedup 1.0000x reference)
//
#include <hip/hip_runtime.h>
#include <stdint.h>

#define AS1 __attribute__((address_space(1)))
#define AS3 __attribute__((address_space(3)))

using bf16x8 = __attribute__((ext_vector_type(8))) short;
using f32x4  = __attribute__((ext_vector_type(4))) float;

// ---- helpers -------------------------------------------------------------
__device__ __forceinline__ unsigned short f2bf(float f) {
  union { float f; unsigned u; } v; v.f = f;
  return (unsigned short)((v.u + 0x7FFFu + ((v.u >> 16) & 1u)) >> 16); // RNE
}
__device__ __forceinline__ float bf2f(unsigned short h) {
  union { unsigned u; float f; } v; v.u = ((unsigned)h) << 16;
  return v.f;
}
// async global->LDS, 16B per lane; lds dest must be wave-uniform base (HW adds lane*16)
__device__ __forceinline__ void gload_lds16(const void* g, void* l) {
  __builtin_amdgcn_global_load_lds((AS1 const void*)g, (AS3 void*)l, 16, 0, 0);
}

// ---- fp32 -> bf16 convert (vectorized, grid-stride) ----------------------
__global__ void k_cvt(const float* __restrict__ in, unsigned short* __restrict__ out, int n4) {
  int idx = blockIdx.x * blockDim.x + threadIdx.x;
  int stride = gridDim.x * blockDim.x;
  for (int i = idx; i < n4; i += stride) {
    float4 f = ((const float4*)in)[i];
    ushort4 o;
    o.x = f2bf(f.x); o.y = f2bf(f.y); o.z = f2bf(f.z); o.w = f2bf(f.w);
    ((ushort4*)out)[i] = o;
  }
}

// ---- RoPE tables: cos/sin[t][i], i in [0,64) ------------------------------
__global__ void k_rope_tables(float* __restrict__ ct, float* __restrict__ st) {
  int idx = blockIdx.x * blockDim.x + threadIdx.x; // T*64 threads
  int t = idx >> 6, i = idx & 63;
  float invf = exp2f(-(float)i * (13.287712379549449f / 64.0f));
  float a = (float)t * invf;
  ct[idx] = cosf(a);
  st[idx] = sinf(a);
}

// ---- RoPE apply in-place on q and k [BH, T, 128] bf16 ---------------------
__global__ void k_rope(unsigned short* __restrict__ q, unsigned short* __restrict__ k,
                       const float* __restrict__ ct, const float* __restrict__ st) {
  int idx = blockIdx.x * blockDim.x + threadIdx.x; // B*H*T*64 threads
  int i = idx & 63;
  int t = (idx >> 6) & 2047;
  int bh = idx >> 17;
  size_t base = ((size_t)bh * 2048 + t) * 128;
  float c = ct[t * 64 + i], s = st[t * 64 + i];
  {
    float x1 = bf2f(q[base + i]), x2 = bf2f(q[base + i + 64]);
    q[base + i]      = f2bf(x1 * c - x2 * s);
    q[base + i + 64] = f2bf(x2 * c + x1 * s);
  }
  {
    float x1 = bf2f(k[base + i]), x2 = bf2f(k[base + i + 64]);
    k[base + i]      = f2bf(x1 * c - x2 * s);
    k[base + i + 64] = f2bf(x2 * c + x1 * s);
  }
}

// ---- GEMM: C = A @ B^T. A:[M,K] bf16 rowmajor, Bw:[N,K] bf16 rowmajor.
// MODE 0: f32 out [M,N]
// MODE 1: bf16 out at [b,h,t,d]  -> Q/K layout
// MODE 2: bf16 out at [b,h,d,t]  -> transposed V layout
template <int MODE>
__global__ __launch_bounds__(256) void k_gemm(const unsigned short* __restrict__ A,
                                              const unsigned short* __restrict__ Bw,
                                              void* __restrict__ Cout,
                                              int M, int N, int K) {
  __shared__ __align__(16) unsigned short As[128 * 64];
  __shared__ __align__(16) unsigned short Bs[128 * 64];

  const int tid = threadIdx.x;
  const int wid = tid >> 6, lane = tid & 63;
  const int wm = wid >> 1, wn = wid & 1;
  const int m0 = blockIdx.y * 128, n0 = blockIdx.x * 128;
  const int rowA = lane & 15;
  const int kgrp = (lane >> 4) * 8;
  const int rgrp = (lane >> 4) * 4;
  const int srow = lane >> 3;
  const int scol = (lane & 7) * 8;

  f32x4 acc[4][4];
  const f32x4 z4 = {0.f, 0.f, 0.f, 0.f};
#pragma unroll
  for (int i = 0; i < 4; ++i)
#pragma unroll
    for (int j = 0; j < 4; ++j) acc[i][j] = z4;

  for (int k0 = 0; k0 < K; k0 += 64) {
    __syncthreads();
#pragma unroll
    for (int i = 0; i < 4; ++i) {
      int c = wid * 4 + i;
      const unsigned short* ga = A  + (size_t)(m0 + c * 8 + srow) * K + k0 + scol;
      gload_lds16(ga, (void*)&As[c * 512]);
      const unsigned short* gb = Bw + (size_t)(n0 + c * 8 + srow) * K + k0 + scol;
      gload_lds16(gb, (void*)&Bs[c * 512]);
    }
    __syncthreads();
#pragma unroll
    for (int kk = 0; kk < 64; kk += 32) {
      bf16x8 af[4], bfv[4];
#pragma unroll
      for (int i = 0; i < 4; ++i)
        af[i] = *(const bf16x8*)&As[(wm * 64 + i * 16 + rowA) * 64 + kk + kgrp];
#pragma unroll
      for (int j = 0; j < 4; ++j)
        bfv[j] = *(const bf16x8*)&Bs[(wn * 64 + j * 16 + rowA) * 64 + kk + kgrp];
#pragma unroll
      for (int i = 0; i < 4; ++i)
#pragma unroll
        for (int j = 0; j < 4; ++j)
          acc[i][j] = __builtin_amdgcn_mfma_f32_16x16x32_bf16(af[i], bfv[j], acc[i][j], 0, 0, 0);
    }
  }

#pragma unroll
  for (int i = 0; i < 4; ++i) {
#pragma unroll
    for (int j = 0; j < 4; ++j) {
      if (MODE == 2) {
        int gn = n0 + wn * 64 + j * 16 + rowA;
        int h = gn >> 7, d = gn & 127;
        int gmb = m0 + wm * 64 + i * 16 + rgrp;
        int b = gmb >> 11, t = gmb & 2047;
        ushort4 pk;
        pk.x = f2bf(acc[i][j][0]); pk.y = f2bf(acc[i][j][1]);
        pk.z = f2bf(acc[i][j][2]); pk.w = f2bf(acc[i][j][3]);
        *(ushort4*)&((unsigned short*)Cout)[(((size_t)(b * 16 + h)) * 128 + d) * 2048 + t] = pk;
      } else {
#pragma unroll
        for (int r = 0; r < 4; ++r) {
          int gm = m0 + wm * 64 + i * 16 + rgrp + r;
          int gn = n0 + wn * 64 + j * 16 + rowA;
          float v = acc[i][j][r];
          if (MODE == 0) {
            ((float*)Cout)[(size_t)gm * N + gn] = v;
          } else {
            int b = gm >> 11, t = gm & 2047;
            int h = gn >> 7, d = gn & 127;
            ((unsigned short*)Cout)[(((size_t)(b * 16 + h)) * 2048 + t) * 128 + d] = f2bf(v);
          }
        }
      }
    }
  }
}

// ---- flash attention fwd: ONE WAVE per block, 32 q rows, KV in 128-wide chunks
// q,k: [BH, 2048, 128] bf16 (post-RoPE); vt: [BH, 128, 2048] bf16
// obt: [B, 2048, 2048] bf16 at (b, t, h*128+d)
__global__ __launch_bounds__(64, 2) void k_flash(const unsigned short* __restrict__ q,
                                                 const unsigned short* __restrict__ k,
                                                 const unsigned short* __restrict__ vt,
                                                 unsigned short* __restrict__ obt) {
  __shared__ __align__(16) unsigned short Plds[32 * 128]; // 8KB, XOR-swizzled

  const int lane = threadIdx.x;
  const int rowA = lane & 15, kgrp = (lane >> 4) * 8, rgrp = (lane >> 4) * 4;
  const int bid = blockIdx.x;
  const int xcd = bid & 7;            // round-robin XCD dispatch assumption (perf-only)
  const int r0  = bid >> 3;
  const int bh  = xcd * 4 + (r0 & 3); // 4 heads per XCD: K+V = 4MB = one L2
  const int j   = 63 - (r0 >> 2);     // heavy q-tiles dispatch first
  const int q0  = j * 32;
  const int b = bh >> 4, h = bh & 15;

  const unsigned short* qh  = q  + (size_t)bh * 2048 * 128;
  const unsigned short* kh  = k  + (size_t)bh * 2048 * 128;
  const unsigned short* vth = vt + (size_t)bh * 128 * 2048;

  bf16x8 qf[2][4];
#pragma unroll
  for (int m = 0; m < 2; ++m)
#pragma unroll
    for (int kq = 0; kq < 4; ++kq)
      qf[m][kq] = *(const bf16x8*)(qh + (size_t)(q0 + m * 16 + rowA) * 128 + kq * 32 + kgrp);

  const f32x4 z4 = {0.f, 0.f, 0.f, 0.f};
  f32x4 o[2][8];
  float mprev[2][4], lsum[2][4];
#pragma unroll
  for (int m = 0; m < 2; ++m) {
#pragma unroll
    for (int dn = 0; dn < 8; ++dn) o[m][dn] = z4;
#pragma unroll
    for (int r = 0; r < 4; ++r) { mprev[m][r] = -1e30f; lsum[m][r] = 0.f; }
  }

  const float sc2 = 0.12751659974141322f; // (1/sqrt(128)) * log2(e): base-2 logits
  const int nc = (q0 >> 7) + 1;           // 128-wide chunks; only last needs mask

  for (int c = 0; c < nc; ++c) {
    const int kv0 = c * 128;

    // ---- S = Q K^T over a 128-wide KV chunk, K direct from L2 ----
    f32x4 s[2][8];
#pragma unroll
    for (int m = 0; m < 2; ++m)
#pragma unroll
      for (int n = 0; n < 8; ++n) s[m][n] = z4;
#pragma unroll
    for (int kq = 0; kq < 4; ++kq) {
      bf16x8 bk[8];
#pragma unroll
      for (int n = 0; n < 8; ++n)
        bk[n] = *(const bf16x8*)(kh + (size_t)(kv0 + n * 16 + rowA) * 128 + kq * 32 + kgrp);
#pragma unroll
      for (int m = 0; m < 2; ++m)
#pragma unroll
        for (int n = 0; n < 8; ++n)
          s[m][n] = __builtin_amdgcn_mfma_f32_16x16x32_bf16(qf[m][kq], bk[n], s[m][n], 0, 0, 0);
    }

    // scale into base-2 logits; causal mask only in the last chunk
    const bool tail = (c == nc - 1);
#pragma unroll
    for (int m = 0; m < 2; ++m)
#pragma unroll
      for (int n = 0; n < 8; ++n)
#pragma unroll
        for (int r = 0; r < 4; ++r) {
          float v = s[m][n][r] * sc2;
          if (tail) {
            int qg = q0 + m * 16 + rgrp + r;
            int kg = kv0 + n * 16 + rowA;
            if (kg > qg) v = -1e30f;
          }
          s[m][n][r] = v;
        }

    // ---- online softmax (base-2), batched shfl trees, defer-max (T13) ----
    float tmax[2][4];
#pragma unroll
    for (int m = 0; m < 2; ++m)
#pragma unroll
      for (int r = 0; r < 4; ++r) {
        float t = s[m][0][r];
#pragma unroll
        for (int n = 1; n < 8; ++n) t = fmaxf(t, s[m][n][r]);
        tmax[m][r] = t;
      }
    // step-major tree: 8 independent shfls per step pipeline in the DS unit
#pragma unroll
    for (int stp = 1; stp <= 8; stp <<= 1)
#pragma unroll
      for (int m = 0; m < 2; ++m)
#pragma unroll
        for (int r = 0; r < 4; ++r)
          tmax[m][r] = fmaxf(tmax[m][r], __shfl_xor(tmax[m][r], stp));

    bool ok = true;
#pragma unroll
    for (int m = 0; m < 2; ++m)
#pragma unroll
      for (int r = 0; r < 4; ++r) ok = ok && (tmax[m][r] <= mprev[m][r] + 8.0f);
    const bool skip = __all(ok ? 1 : 0);

    float mnew[2][4], psum[2][4];
#pragma unroll
    for (int m = 0; m < 2; ++m)
#pragma unroll
      for (int r = 0; r < 4; ++r) {
        mnew[m][r] = skip ? mprev[m][r] : fmaxf(mprev[m][r], tmax[m][r]);
        float ps = 0.f;
#pragma unroll
        for (int n = 0; n < 8; ++n) {
          float p = exp2f(s[m][n][r] - mnew[m][r]);
          s[m][n][r] = p;
          ps += p;
        }
        psum[m][r] = ps;
      }
#pragma unroll
    for (int stp = 1; stp <= 8; stp <<= 1)
#pragma unroll
      for (int m = 0; m < 2; ++m)
#pragma unroll
        for (int r = 0; r < 4; ++r)
          psum[m][r] += __shfl_xor(psum[m][r], stp);

#pragma unroll
    for (int m = 0; m < 2; ++m)
#pragma unroll
      for (int r = 0; r < 4; ++r) {
        if (skip) {
          lsum[m][r] += psum[m][r];
        } else {
          float alpha = exp2f(mprev[m][r] - mnew[m][r]);
          lsum[m][r] = lsum[m][r] * alpha + psum[m][r];
          mprev[m][r] = mnew[m][r];
#pragma unroll
          for (int dn = 0; dn < 8; ++dn) o[m][dn][r] *= alpha;
        }
      }

    // ---- P: C/D-frag layout -> A-operand layout via swizzled LDS ----
#pragma unroll
    for (int m = 0; m < 2; ++m)
#pragma unroll
      for (int n = 0; n < 8; ++n)
#pragma unroll
        for (int r = 0; r < 4; ++r) {
          int row = m * 16 + rgrp + r;
          int col = n * 16 + rowA;
          Plds[row * 128 + (col ^ ((row & 7) << 3))] = f2bf(s[m][n][r]);
        }
    // single wave: DS ops retire in order; compiler inserts lgkmcnt waits

    // ---- O += P @ V, V direct from L2 (transposed layout) ----
#pragma unroll
    for (int kk = 0; kk < 4; ++kk) {
      bf16x8 pa[2];
#pragma unroll
      for (int m = 0; m < 2; ++m) {
        int row = m * 16 + rowA;
        int col0 = kk * 32 + kgrp;
        pa[m] = *(const bf16x8*)&Plds[row * 128 + (col0 ^ ((row & 7) << 3))];
      }
#pragma unroll
      for (int dn = 0; dn < 8; ++dn) {
        bf16x8 vb = *(const bf16x8*)(vth + (size_t)(dn * 16 + rowA) * 2048 + kv0 + kk * 32 + kgrp);
#pragma unroll
        for (int m = 0; m < 2; ++m)
          o[m][dn] = __builtin_amdgcn_mfma_f32_16x16x32_bf16(pa[m], vb, o[m][dn], 0, 0, 0);
      }
    }
  }

  // epilogue: normalize and write bf16 [B,T,C]
#pragma unroll
  for (int m = 0; m < 2; ++m)
#pragma unroll
    for (int dn = 0; dn < 8; ++dn)
#pragma unroll
      for (int r = 0; r < 4; ++r) {
        float v = o[m][dn][r] / lsum[m][r];
        int t = q0 + m * 16 + rgrp + r;
        int col = h * 128 + dn * 16 + rowA;
        obt[((size_t)b * 2048 + t) * 2048 + col] = f2bf(v);
      }
}

// ---- host launch -----------------------------------------------------------
extern "C" void kernel_launch(void* const* d_in, const int* in_sizes, int n_in,
                              void* d_out, int out_size, void* d_ws, size_t ws_size,
                              hipStream_t stream) {
  const float* x  = (const float*)d_in[0];
  const float* Wq = (const float*)d_in[2];
  const float* Wk = (const float*)d_in[3];
  const float* Wv = (const float*)d_in[4];
  const float* Wo = (const float*)d_in[5];
  float* out = (float*)d_out;

  char* ws = (char*)d_ws;
  unsigned short* xb  = (unsigned short*)(ws + 0);
  unsigned short* wqb = (unsigned short*)(ws + 16777216);
  unsigned short* wkb = (unsigned short*)(ws + 25165824);
  unsigned short* wvb = (unsigned short*)(ws + 33554432);
  unsigned short* wob = (unsigned short*)(ws + 41943040);
  unsigned short* qb  = (unsigned short*)(ws + 50331648);
  unsigned short* kb  = (unsigned short*)(ws + 67108864);
  unsigned short* vtb = (unsigned short*)(ws + 83886080);
  unsigned short* obt = (unsigned short*)(ws + 100663296);
  float* ct = (float*)(ws + 117440512);
  float* st = (float*)(ws + 117964800);

  k_cvt<<<2048, 256, 0, stream>>>(x,  xb,  2097152);
  k_cvt<<<1024, 256, 0, stream>>>(Wq, wqb, 1048576);
  k_cvt<<<1024, 256, 0, stream>>>(Wk, wkb, 1048576);
  k_cvt<<<1024, 256, 0, stream>>>(Wv, wvb, 1048576);
  k_cvt<<<1024, 256, 0, stream>>>(Wo, wob, 1048576);
  k_rope_tables<<<512, 256, 0, stream>>>(ct, st);
  dim3 gg(16, 32);
  k_gemm<1><<<gg, 256, 0, stream>>>(xb, wqb, (void*)qb,  4096, 2048, 2048);
  k_gemm<1><<<gg, 256, 0, stream>>>(xb, wkb, (void*)kb,  4096, 2048, 2048);
  k_gemm<2><<<gg, 256, 0, stream>>>(xb, wvb, (void*)vtb, 4096, 2048, 2048);
  k_rope<<<16384, 256, 0, stream>>>(qb, kb, ct, st);
  k_flash<<<2048, 64, 0, stream>>>(qb, kb, vtb, obt);
  k_gemm<0><<<gg, 256, 0, stream>>>(obt, wob, (void*)out, 4096, 2048, 2048);
}

// Round 4
// 387.410 us; speedup vs baseline: 1.5469x; 1.5469x over previous
//
#include <hip/hip_runtime.h>
#include <stdint.h>

#define AS1 __attribute__((address_space(1)))
#define AS3 __attribute__((address_space(3)))

using bf16x8 = __attribute__((ext_vector_type(8))) short;
using f32x4  = __attribute__((ext_vector_type(4))) float;

// ---- helpers -------------------------------------------------------------
__device__ __forceinline__ unsigned short f2bf(float f) {
  union { float f; unsigned u; } v; v.f = f;
  return (unsigned short)((v.u + 0x7FFFu + ((v.u >> 16) & 1u)) >> 16); // RNE
}
__device__ __forceinline__ float bf2f(unsigned short h) {
  union { unsigned u; float f; } v; v.u = ((unsigned)h) << 16;
  return v.f;
}
// async global->LDS, 16B per lane; lds dest must be wave-uniform base (HW adds lane*16)
__device__ __forceinline__ void gload_lds16(const void* g, void* l) {
  __builtin_amdgcn_global_load_lds((AS1 const void*)g, (AS3 void*)l, 16, 0, 0);
}

// ---- fp32 -> bf16 convert (vectorized, grid-stride) ----------------------
__global__ void k_cvt(const float* __restrict__ in, unsigned short* __restrict__ out, int n4) {
  int idx = blockIdx.x * blockDim.x + threadIdx.x;
  int stride = gridDim.x * blockDim.x;
  for (int i = idx; i < n4; i += stride) {
    float4 f = ((const float4*)in)[i];
    ushort4 o;
    o.x = f2bf(f.x); o.y = f2bf(f.y); o.z = f2bf(f.z); o.w = f2bf(f.w);
    ((ushort4*)out)[i] = o;
  }
}

// ---- RoPE tables: cos/sin[t][i], i in [0,64) ------------------------------
__global__ void k_rope_tables(float* __restrict__ ct, float* __restrict__ st) {
  int idx = blockIdx.x * blockDim.x + threadIdx.x; // T*64 threads
  int t = idx >> 6, i = idx & 63;
  float invf = exp2f(-(float)i * (13.287712379549449f / 64.0f));
  float a = (float)t * invf;
  ct[idx] = cosf(a);
  st[idx] = sinf(a);
}

// ---- RoPE apply in-place on q and k [BH, T, 128] bf16 ---------------------
__global__ void k_rope(unsigned short* __restrict__ q, unsigned short* __restrict__ k,
                       const float* __restrict__ ct, const float* __restrict__ st) {
  int idx = blockIdx.x * blockDim.x + threadIdx.x; // B*H*T*64 threads
  int i = idx & 63;
  int t = (idx >> 6) & 2047;
  int bh = idx >> 17;
  size_t base = ((size_t)bh * 2048 + t) * 128;
  float c = ct[t * 64 + i], s = st[t * 64 + i];
  {
    float x1 = bf2f(q[base + i]), x2 = bf2f(q[base + i + 64]);
    q[base + i]      = f2bf(x1 * c - x2 * s);
    q[base + i + 64] = f2bf(x2 * c + x1 * s);
  }
  {
    float x1 = bf2f(k[base + i]), x2 = bf2f(k[base + i + 64]);
    k[base + i]      = f2bf(x1 * c - x2 * s);
    k[base + i + 64] = f2bf(x2 * c + x1 * s);
  }
}

// ---- GEMM: C = A @ B^T. A:[M,K] bf16 rowmajor, Bw:[N,K] bf16 rowmajor.
// MODE 0: f32 out [M,N]
// MODE 1: bf16 out at [b,h,t,d]  -> Q/K layout
// MODE 2: bf16 out at [b,h,d,t]  -> transposed V layout
template <int MODE>
__global__ __launch_bounds__(256) void k_gemm(const unsigned short* __restrict__ A,
                                              const unsigned short* __restrict__ Bw,
                                              void* __restrict__ Cout,
                                              int M, int N, int K) {
  __shared__ __align__(16) unsigned short As[128 * 64];
  __shared__ __align__(16) unsigned short Bs[128 * 64];

  const int tid = threadIdx.x;
  const int wid = tid >> 6, lane = tid & 63;
  const int wm = wid >> 1, wn = wid & 1;
  const int m0 = blockIdx.y * 128, n0 = blockIdx.x * 128;
  const int rowA = lane & 15;
  const int kgrp = (lane >> 4) * 8;
  const int rgrp = (lane >> 4) * 4;
  const int srow = lane >> 3;
  const int scol = (lane & 7) * 8;

  f32x4 acc[4][4];
  const f32x4 z4 = {0.f, 0.f, 0.f, 0.f};
#pragma unroll
  for (int i = 0; i < 4; ++i)
#pragma unroll
    for (int j = 0; j < 4; ++j) acc[i][j] = z4;

  for (int k0 = 0; k0 < K; k0 += 64) {
    __syncthreads();
#pragma unroll
    for (int i = 0; i < 4; ++i) {
      int c = wid * 4 + i;
      const unsigned short* ga = A  + (size_t)(m0 + c * 8 + srow) * K + k0 + scol;
      gload_lds16(ga, (void*)&As[c * 512]);
      const unsigned short* gb = Bw + (size_t)(n0 + c * 8 + srow) * K + k0 + scol;
      gload_lds16(gb, (void*)&Bs[c * 512]);
    }
    __syncthreads();
#pragma unroll
    for (int kk = 0; kk < 64; kk += 32) {
      bf16x8 af[4], bfv[4];
#pragma unroll
      for (int i = 0; i < 4; ++i)
        af[i] = *(const bf16x8*)&As[(wm * 64 + i * 16 + rowA) * 64 + kk + kgrp];
#pragma unroll
      for (int j = 0; j < 4; ++j)
        bfv[j] = *(const bf16x8*)&Bs[(wn * 64 + j * 16 + rowA) * 64 + kk + kgrp];
#pragma unroll
      for (int i = 0; i < 4; ++i)
#pragma unroll
        for (int j = 0; j < 4; ++j)
          acc[i][j] = __builtin_amdgcn_mfma_f32_16x16x32_bf16(af[i], bfv[j], acc[i][j], 0, 0, 0);
    }
  }

#pragma unroll
  for (int i = 0; i < 4; ++i) {
#pragma unroll
    for (int j = 0; j < 4; ++j) {
      if (MODE == 2) {
        int gn = n0 + wn * 64 + j * 16 + rowA;
        int h = gn >> 7, d = gn & 127;
        int gmb = m0 + wm * 64 + i * 16 + rgrp;
        int b = gmb >> 11, t = gmb & 2047;
        ushort4 pk;
        pk.x = f2bf(acc[i][j][0]); pk.y = f2bf(acc[i][j][1]);
        pk.z = f2bf(acc[i][j][2]); pk.w = f2bf(acc[i][j][3]);
        *(ushort4*)&((unsigned short*)Cout)[(((size_t)(b * 16 + h)) * 128 + d) * 2048 + t] = pk;
      } else {
#pragma unroll
        for (int r = 0; r < 4; ++r) {
          int gm = m0 + wm * 64 + i * 16 + rgrp + r;
          int gn = n0 + wn * 64 + j * 16 + rowA;
          float v = acc[i][j][r];
          if (MODE == 0) {
            ((float*)Cout)[(size_t)gm * N + gn] = v;
          } else {
            int b = gm >> 11, t = gm & 2047;
            int h = gn >> 7, d = gn & 127;
            ((unsigned short*)Cout)[(((size_t)(b * 16 + h)) * 2048 + t) * 128 + d] = f2bf(v);
          }
        }
      }
    }
  }
}

// ---- flash attention fwd: ONE WAVE per block, 32 q rows, 64-wide KV tiles
// Per tile: batch-load K (1 vmcnt wait), QK^T, issue all V loads, softmax
// (hides V latency), P->LDS->A-frag, PV. K/V are L2-resident (4 heads/XCD).
__global__ __launch_bounds__(64) void k_flash(const unsigned short* __restrict__ q,
                                              const unsigned short* __restrict__ k,
                                              const unsigned short* __restrict__ vt,
                                              unsigned short* __restrict__ obt) {
  __shared__ __align__(16) unsigned short Plds[32 * 64]; // 4KB, XOR-swizzled

  const int lane = threadIdx.x;
  const int rowA = lane & 15, kgrp = (lane >> 4) * 8, rgrp = (lane >> 4) * 4;
  const int bid = blockIdx.x;
  const int xcd = bid & 7;            // round-robin XCD dispatch assumption (perf-only)
  const int r0  = bid >> 3;
  const int bh  = xcd * 4 + (r0 & 3); // 4 heads per XCD: K+V = 4MB = one L2
  const int j   = 63 - (r0 >> 2);     // heavy q-tiles dispatch first
  const int q0  = j * 32;
  const int b = bh >> 4, h = bh & 15;

  const unsigned short* qh  = q  + (size_t)bh * 2048 * 128;
  const unsigned short* kh  = k  + (size_t)bh * 2048 * 128;
  const unsigned short* vth = vt + (size_t)bh * 128 * 2048;

  bf16x8 qf[2][4];
#pragma unroll
  for (int m = 0; m < 2; ++m)
#pragma unroll
    for (int kq = 0; kq < 4; ++kq)
      qf[m][kq] = *(const bf16x8*)(qh + (size_t)(q0 + m * 16 + rowA) * 128 + kq * 32 + kgrp);

  const f32x4 z4 = {0.f, 0.f, 0.f, 0.f};
  f32x4 o[2][8];
  float mprev[2][4], lsum[2][4];
#pragma unroll
  for (int m = 0; m < 2; ++m) {
#pragma unroll
    for (int dn = 0; dn < 8; ++dn) o[m][dn] = z4;
#pragma unroll
    for (int r = 0; r < 4; ++r) { mprev[m][r] = -1e30f; lsum[m][r] = 0.f; }
  }

  const float sc2 = 0.12751659974141322f; // (1/sqrt(128)) * log2(e): base-2 logits
  const int nt = (q0 >> 6) + 1;           // 64-wide tiles; only last needs mask

  for (int it = 0; it < nt; ++it) {
    const int kv0 = it * 64;

    // ---- batch-load ALL K fragments for this tile (one wait, 16 loads in flight)
    bf16x8 kreg[4][4]; // [kq][n]
#pragma unroll
    for (int kq = 0; kq < 4; ++kq)
#pragma unroll
      for (int n = 0; n < 4; ++n)
        kreg[kq][n] = *(const bf16x8*)(kh + (size_t)(kv0 + n * 16 + rowA) * 128 + kq * 32 + kgrp);

    // ---- S = Q K^T
    f32x4 s[2][4];
#pragma unroll
    for (int m = 0; m < 2; ++m)
#pragma unroll
      for (int n = 0; n < 4; ++n) s[m][n] = z4;
#pragma unroll
    for (int kq = 0; kq < 4; ++kq)
#pragma unroll
      for (int m = 0; m < 2; ++m)
#pragma unroll
        for (int n = 0; n < 4; ++n)
          s[m][n] = __builtin_amdgcn_mfma_f32_16x16x32_bf16(qf[m][kq], kreg[kq][n], s[m][n], 0, 0, 0);

    // ---- issue ALL V loads now; consumed only after softmax (latency hidden)
    bf16x8 vreg[2][8]; // [kk][dn]
#pragma unroll
    for (int kk = 0; kk < 2; ++kk)
#pragma unroll
      for (int dn = 0; dn < 8; ++dn)
        vreg[kk][dn] = *(const bf16x8*)(vth + (size_t)(dn * 16 + rowA) * 2048 + kv0 + kk * 32 + kgrp);

    // scale into base-2 logits; causal mask only in the last tile
    const bool tail = (it == nt - 1);
#pragma unroll
    for (int m = 0; m < 2; ++m)
#pragma unroll
      for (int n = 0; n < 4; ++n)
#pragma unroll
        for (int r = 0; r < 4; ++r) {
          float v = s[m][n][r] * sc2;
          if (tail) {
            int qg = q0 + m * 16 + rgrp + r;
            int kg = kv0 + n * 16 + rowA;
            if (kg > qg) v = -1e30f;
          }
          s[m][n][r] = v;
        }

    // ---- online softmax (base-2), step-major shfl trees, defer-max (T13) ----
    float tmax[2][4];
#pragma unroll
    for (int m = 0; m < 2; ++m)
#pragma unroll
      for (int r = 0; r < 4; ++r)
        tmax[m][r] = fmaxf(fmaxf(s[m][0][r], s[m][1][r]), fmaxf(s[m][2][r], s[m][3][r]));
#pragma unroll
    for (int stp = 1; stp <= 8; stp <<= 1)
#pragma unroll
      for (int m = 0; m < 2; ++m)
#pragma unroll
        for (int r = 0; r < 4; ++r)
          tmax[m][r] = fmaxf(tmax[m][r], __shfl_xor(tmax[m][r], stp));

    bool ok = true;
#pragma unroll
    for (int m = 0; m < 2; ++m)
#pragma unroll
      for (int r = 0; r < 4; ++r) ok = ok && (tmax[m][r] <= mprev[m][r] + 8.0f);
    const bool skip = __all(ok ? 1 : 0);

    float mnew[2][4], psum[2][4];
#pragma unroll
    for (int m = 0; m < 2; ++m)
#pragma unroll
      for (int r = 0; r < 4; ++r) {
        mnew[m][r] = skip ? mprev[m][r] : fmaxf(mprev[m][r], tmax[m][r]);
        float ps = 0.f;
#pragma unroll
        for (int n = 0; n < 4; ++n) {
          float p = exp2f(s[m][n][r] - mnew[m][r]);
          s[m][n][r] = p;
          ps += p;
        }
        psum[m][r] = ps;
      }
#pragma unroll
    for (int stp = 1; stp <= 8; stp <<= 1)
#pragma unroll
      for (int m = 0; m < 2; ++m)
#pragma unroll
        for (int r = 0; r < 4; ++r)
          psum[m][r] += __shfl_xor(psum[m][r], stp);

#pragma unroll
    for (int m = 0; m < 2; ++m)
#pragma unroll
      for (int r = 0; r < 4; ++r) {
        if (skip) {
          lsum[m][r] += psum[m][r];
        } else {
          float alpha = exp2f(mprev[m][r] - mnew[m][r]);
          lsum[m][r] = lsum[m][r] * alpha + psum[m][r];
          mprev[m][r] = mnew[m][r];
#pragma unroll
          for (int dn = 0; dn < 8; ++dn) o[m][dn][r] *= alpha;
        }
      }

    // ---- P: C/D-frag layout -> A-operand layout via swizzled LDS ----
#pragma unroll
    for (int m = 0; m < 2; ++m)
#pragma unroll
      for (int n = 0; n < 4; ++n)
#pragma unroll
        for (int r = 0; r < 4; ++r) {
          int row = m * 16 + rgrp + r;
          int col = n * 16 + rowA;
          Plds[row * 64 + (col ^ ((row & 7) << 3))] = f2bf(s[m][n][r]);
        }
    // single wave: DS ops retire in order; compiler inserts lgkmcnt waits

    bf16x8 pa[2][2];
#pragma unroll
    for (int m = 0; m < 2; ++m)
#pragma unroll
      for (int kk = 0; kk < 2; ++kk) {
        int row = m * 16 + rowA;
        int col0 = kk * 32 + kgrp;
        pa[m][kk] = *(const bf16x8*)&Plds[row * 64 + (col0 ^ ((row & 7) << 3))];
      }

    // ---- O += P @ V (V already in registers) ----
#pragma unroll
    for (int kk = 0; kk < 2; ++kk)
#pragma unroll
      for (int dn = 0; dn < 8; ++dn)
#pragma unroll
        for (int m = 0; m < 2; ++m)
          o[m][dn] = __builtin_amdgcn_mfma_f32_16x16x32_bf16(pa[m][kk], vreg[kk][dn], o[m][dn], 0, 0, 0);
  }

  // epilogue: normalize (one reciprocal per row) and write bf16 [B,T,C]
  float rinv[2][4];
#pragma unroll
  for (int m = 0; m < 2; ++m)
#pragma unroll
    for (int r = 0; r < 4; ++r) rinv[m][r] = 1.0f / lsum[m][r];
#pragma unroll
  for (int m = 0; m < 2; ++m)
#pragma unroll
    for (int dn = 0; dn < 8; ++dn)
#pragma unroll
      for (int r = 0; r < 4; ++r) {
        float v = o[m][dn][r] * rinv[m][r];
        int t = q0 + m * 16 + rgrp + r;
        int col = h * 128 + dn * 16 + rowA;
        obt[((size_t)b * 2048 + t) * 2048 + col] = f2bf(v);
      }
}

// ---- host launch -----------------------------------------------------------
extern "C" void kernel_launch(void* const* d_in, const int* in_sizes, int n_in,
                              void* d_out, int out_size, void* d_ws, size_t ws_size,
                              hipStream_t stream) {
  const float* x  = (const float*)d_in[0];
  const float* Wq = (const float*)d_in[2];
  const float* Wk = (const float*)d_in[3];
  const float* Wv = (const float*)d_in[4];
  const float* Wo = (const float*)d_in[5];
  float* out = (float*)d_out;

  char* ws = (char*)d_ws;
  unsigned short* xb  = (unsigned short*)(ws + 0);
  unsigned short* wqb = (unsigned short*)(ws + 16777216);
  unsigned short* wkb = (unsigned short*)(ws + 25165824);
  unsigned short* wvb = (unsigned short*)(ws + 33554432);
  unsigned short* wob = (unsigned short*)(ws + 41943040);
  unsigned short* qb  = (unsigned short*)(ws + 50331648);
  unsigned short* kb  = (unsigned short*)(ws + 67108864);
  unsigned short* vtb = (unsigned short*)(ws + 83886080);
  unsigned short* obt = (unsigned short*)(ws + 100663296);
  float* ct = (float*)(ws + 117440512);
  float* st = (float*)(ws + 117964800);

  k_cvt<<<2048, 256, 0, stream>>>(x,  xb,  2097152);
  k_cvt<<<1024, 256, 0, stream>>>(Wq, wqb, 1048576);
  k_cvt<<<1024, 256, 0, stream>>>(Wk, wkb, 1048576);
  k_cvt<<<1024, 256, 0, stream>>>(Wv, wvb, 1048576);
  k_cvt<<<1024, 256, 0, stream>>>(Wo, wob, 1048576);
  k_rope_tables<<<512, 256, 0, stream>>>(ct, st);
  dim3 gg(16, 32);
  k_gemm<1><<<gg, 256, 0, stream>>>(xb, wqb, (void*)qb,  4096, 2048, 2048);
  k_gemm<1><<<gg, 256, 0, stream>>>(xb, wkb, (void*)kb,  4096, 2048, 2048);
  k_gemm<2><<<gg, 256, 0, stream>>>(xb, wvb, (void*)vtb, 4096, 2048, 2048);
  k_rope<<<16384, 256, 0, stream>>>(qb, kb, ct, st);
  k_flash<<<2048, 64, 0, stream>>>(qb, kb, vtb, obt);
  k_gemm<0><<<gg, 256, 0, stream>>>(obt, wob, (void*)out, 4096, 2048, 2048);
}